// Round 4
// baseline (179.183 us; speedup 1.0000x reference)
//
#include <hip/hip_runtime.h>
#include <stdint.h>

typedef __attribute__((ext_vector_type(8))) short  bf16x8;
typedef __attribute__((ext_vector_type(4))) short  short4v;
typedef __attribute__((ext_vector_type(4))) float  f32x4;
typedef __attribute__((ext_vector_type(4))) float  float4v;

__device__ __forceinline__ unsigned short f2bf(float f) {
  unsigned int u = __builtin_bit_cast(unsigned int, f);
  u += 0x7FFFu + ((u >> 16) & 1u);          // round-to-nearest-even
  return (unsigned short)(u >> 16);
}

__device__ __forceinline__ void async_ld16(const void* g, void* l) {
  __builtin_amdgcn_global_load_lds(
      (const __attribute__((address_space(1))) void*)g,
      (__attribute__((address_space(3))) void*)l,
      16, 0, 0);
}

// ----------------------------------------------------------- fused prep ----
// blocks [0,8192): cast x->bf16 ; [8192,11264): Wqkv^T ; [11264,12288): Wproj^T
__global__ __launch_bounds__(256) void prep(
    const float* __restrict__ x, const float* __restrict__ Wqkv,
    const float* __restrict__ Wproj,
    unsigned short* __restrict__ xb, unsigned short* __restrict__ wqkvT,
    unsigned short* __restrict__ wprojT) {
  __shared__ float tile[32][33];
  const int b = blockIdx.x, tid = threadIdx.x;
  if (b < 8192) {
    int i = b * 256 + tid;
    float4v v = *(const float4v*)(x + (size_t)i * 4);
    short4v o;
    o[0] = (short)f2bf(v[0]); o[1] = (short)f2bf(v[1]);
    o[2] = (short)f2bf(v[2]); o[3] = (short)f2bf(v[3]);
    *(short4v*)(xb + (size_t)i * 4) = o;
    return;
  }
  const float* in; unsigned short* out; int R, C, bx, by;
  if (b < 11264) { int t = b - 8192;  in = Wqkv;  out = wqkvT;  R = 1024; C = 3072; bx = t % 96; by = t / 96; }
  else           { int t = b - 11264; in = Wproj; out = wprojT; R = 1024; C = 1024; bx = t & 31; by = t >> 5; }
  const int tx = tid & 31, ty = tid >> 5;
  const int c0 = bx * 32, r0 = by * 32;
  #pragma unroll
  for (int rr = ty; rr < 32; rr += 8)
    tile[rr][tx] = in[(size_t)(r0 + rr) * C + c0 + tx];
  __syncthreads();
  #pragma unroll
  for (int cc = ty; cc < 32; cc += 8)
    out[(size_t)(c0 + cc) * R + r0 + tx] = f2bf(tile[tx][cc]);
}

// ------------------------------------------------- multi-resident GEMM ----
// C[M,N] = A[M,K]*BT[N,K]^T. 4 waves/block (2M x WN), tile (AJ*64)x(BJ*64),
// BK=32, double-buffered LDS (XOR-swizzled), stage-early/vmcnt-late,
// OCC blocks/CU co-resident for TLP hiding. Grid sized to exact residency.
template<int MT, int NTF, int WN, int AJ, int BJ, int OCC, int BF16_OUT>
__global__ __launch_bounds__(256, OCC) void gemm_p(
    const unsigned short* __restrict__ A,
    const unsigned short* __restrict__ BT,
    void* __restrict__ Cout, const float* __restrict__ bias,
    int M, int N, int K) {
  constexpr int RA = AJ * 64;            // tile rows (M)
  constexpr int RB = BJ * 64;            // tile cols (N)
  __shared__ __align__(16) unsigned short lsA[2 * RA * 32];
  __shared__ __align__(16) unsigned short lsB[2 * RB * 32];
  const int tid = threadIdx.x;
  const int ln = tid & 63, w = tid >> 6;
  const int lr = ln & 15, lq = ln >> 4;
  const int wm = w / WN, wn = w % WN;

  // XCD chunked swizzle (grids are exact multiples of 8)
  int wid = blockIdx.y * gridDim.x + blockIdx.x;
  const int nwg = gridDim.x * gridDim.y;
  { const int q = nwg >> 3; wid = (wid & 7) * q + (wid >> 3); }
  const int bm = (wid / gridDim.x) * RA, bn = (wid % gridDim.x) * RB;

  // ---- staging: linear LDS dest, source k-chunk pre-swizzled ----
  const int srow = tid >> 2;
  const int kc = ((tid & 3) ^ ((tid >> 3) & 3)) * 8;
  const unsigned short* gA = A  + (size_t)(bm + srow) * K + kc;
  const unsigned short* gB = BT + (size_t)(bn + srow) * K + kc;
  char* lA = (char*)lsA + tid * 16;
  char* lB = (char*)lsB + tid * 16;

#define STAGE(s, c) do {                                                     \
    _Pragma("unroll")                                                        \
    for (int j = 0; j < AJ; ++j)                                             \
      async_ld16(gA + (size_t)(c) * 32 + (size_t)j * 64 * K,                 \
                 lA + (s) * (RA * 64) + j * 4096);                           \
    _Pragma("unroll")                                                        \
    for (int j = 0; j < BJ; ++j)                                             \
      async_ld16(gB + (size_t)(c) * 32 + (size_t)j * 64 * K,                 \
                 lB + (s) * (RB * 64) + j * 4096);                           \
  } while (0)

  // ---- swizzled fragment read bases (slot = lq ^ ((row>>1)&3)) ----
  const int asl = (lq ^ ((lr >> 1) & 3)) << 4;
  const char* rA = (const char*)lsA + (wm * (MT * 16) + lr) * 64 + asl;
  const char* rB = (const char*)lsB + (wn * (NTF * 16) + lr) * 64 + asl;

  f32x4 acc[MT][NTF] = {};

  STAGE(0, 0);
  asm volatile("s_waitcnt vmcnt(0)" ::: "memory");
  __builtin_amdgcn_sched_barrier(0);
  __builtin_amdgcn_s_barrier();

  const int NK = K / 32;
  for (int c = 0; c < NK; ++c) {
    const int cur = c & 1;
    if (c + 1 < NK) STAGE(cur ^ 1, c + 1);     // issue early: hidden under MFMA
    const char* pA = rA + cur * (RA * 64);
    const char* pB = rB + cur * (RB * 64);
    bf16x8 bb[NTF];
    #pragma unroll
    for (int nf = 0; nf < NTF; ++nf) bb[nf] = *(const bf16x8*)(pB + nf * 1024);
    #pragma unroll
    for (int mh = 0; mh < MT; mh += 4) {       // 4-row-frag batches: VGPR cap
      bf16x8 aa[4];
      #pragma unroll
      for (int i = 0; i < 4; ++i) aa[i] = *(const bf16x8*)(pA + (mh + i) * 1024);
      __builtin_amdgcn_s_setprio(1);
      #pragma unroll
      for (int mf = 0; mf < 4; ++mf)
        #pragma unroll
        for (int nf = 0; nf < NTF; ++nf)
          acc[mh + mf][nf] = __builtin_amdgcn_mfma_f32_16x16x32_bf16(
              aa[mf], bb[nf], acc[mh + mf][nf], 0, 0, 0);
      __builtin_amdgcn_s_setprio(0);
    }
    asm volatile("s_waitcnt vmcnt(0)" ::: "memory");   // next tile landed
    __builtin_amdgcn_sched_barrier(0);
    __builtin_amdgcn_s_barrier();
  }
#undef STAGE

  // ---- epilogue ----
  const int c0 = bn + wn * (NTF * 16) + lr;
  if (BF16_OUT) {
    unsigned short* C = (unsigned short*)Cout;
    #pragma unroll
    for (int mf = 0; mf < MT; ++mf)
      #pragma unroll
      for (int i = 0; i < 4; ++i) {
        size_t r = (size_t)(bm + wm * (MT * 16) + mf * 16 + lq * 4 + i);
        #pragma unroll
        for (int nf = 0; nf < NTF; ++nf)
          C[r * N + c0 + nf * 16] = f2bf(acc[mf][nf][i]);
      }
  } else {
    float* C = (float*)Cout;
    float bv[NTF];
    #pragma unroll
    for (int nf = 0; nf < NTF; ++nf) bv[nf] = bias ? bias[c0 + nf * 16] : 0.f;
    #pragma unroll
    for (int mf = 0; mf < MT; ++mf)
      #pragma unroll
      for (int i = 0; i < 4; ++i) {
        size_t r = (size_t)(bm + wm * (MT * 16) + mf * 16 + lq * 4 + i);
        #pragma unroll
        for (int nf = 0; nf < NTF; ++nf)
          C[r * N + c0 + nf * 16] = acc[mf][nf][i] + bv[nf];
      }
  }
}

// --------------------------------- partial M^T = scale*(k^T v)^T over j ----
// block = unit*4 + p ; unit = b*32 + h*2 + half ; p = j-quarter (256 rows)
__global__ __launch_bounds__(256) void kv_outer(
    const unsigned short* __restrict__ qkv,
    unsigned short* __restrict__ MT, float scale) {
  const int bid = blockIdx.x;
  const int p = bid & 3, unit = bid >> 2;
  const int b = unit >> 5, h = (unit >> 1) & 15, hf = unit & 1;
  const size_t base = ((size_t)(b * 2048 + hf * 1024)) * 3072 + h * 64;
  const unsigned short* kp = qkv + base + 1024;
  const unsigned short* vp = qkv + base + 2048;
  __shared__ __align__(16) unsigned short kT[64][136];
  __shared__ __align__(16) unsigned short vT[64][136];
  const int tid = threadIdx.x, wv = tid >> 6, ln = tid & 63;
  f32x4 acc[4] = {};
  const int e4 = (tid & 15) * 4;
  const int jr = tid >> 4;
  const int fr = ln & 15, ko = (ln >> 4) * 8;

  for (int j0 = p * 256; j0 < p * 256 + 256; j0 += 128) {
    __syncthreads();
    #pragma unroll
    for (int jj = 0; jj < 128; jj += 16) {
      int j = jj + jr;
      size_t go = (size_t)(j0 + j) * 3072 + e4;
      short4v k4 = *(const short4v*)(kp + go);
      short4v v4 = *(const short4v*)(vp + go);
      #pragma unroll
      for (int t = 0; t < 4; t++) {
        kT[e4 + t][j] = (unsigned short)k4[t];
        vT[e4 + t][j] = (unsigned short)v4[t];
      }
    }
    __syncthreads();
    #pragma unroll
    for (int kk = 0; kk < 128; kk += 32) {
      bf16x8 af = *(const bf16x8*)&kT[wv * 16 + fr][kk + ko];
      #pragma unroll
      for (int n = 0; n < 4; n++) {
        bf16x8 bf2 = *(const bf16x8*)&vT[n * 16 + fr][kk + ko];
        acc[n] = __builtin_amdgcn_mfma_f32_16x16x32_bf16(af, bf2, acc[n], 0, 0, 0);
      }
    }
  }
  unsigned short* outp = MT + (size_t)bid * 4096;       // [d][e], 64x64
  #pragma unroll
  for (int n = 0; n < 4; n++)
    #pragma unroll
    for (int i = 0; i < 4; i++) {
      int d = n * 16 + fr;
      int e = wv * 16 + (ln >> 4) * 4 + i;
      outp[d * 64 + e] = f2bf(acc[n][i] * scale);
    }
}

// ---------------------------------------------- o = q * sum_p M_p ----------
__global__ __launch_bounds__(256) void apply_q(
    const unsigned short* __restrict__ qkv,
    const unsigned short* __restrict__ MT,
    unsigned short* __restrict__ o) {
  const int bid = blockIdx.x;     // ((b*16+h)*2 + lhalf)*16 + lt
  const int lt = bid & 15, hf = (bid >> 4) & 1, h = (bid >> 5) & 15, b = bid >> 9;
  const int l0 = hf * 1024 + lt * 64;
  const unsigned short* qp = qkv + ((size_t)(b * 2048 + l0)) * 3072 + h * 64;
  const int unit_other = (b * 16 + h) * 2 + (1 - hf);
  const unsigned short* mp = MT + (size_t)unit_other * 4 * 4096;
  const int tid = threadIdx.x, wv = tid >> 6, ln = tid & 63;
  const int fr = ln & 15, ko = (ln >> 4) * 8;
  f32x4 acc[4] = {};
  bf16x8 af[2];
  #pragma unroll
  for (int kk = 0; kk < 2; kk++)
    af[kk] = *(const bf16x8*)(qp + (size_t)(wv * 16 + fr) * 3072 + kk * 32 + ko);
  #pragma unroll
  for (int p = 0; p < 4; ++p)
    #pragma unroll
    for (int kk = 0; kk < 2; kk++)
      #pragma unroll
      for (int n = 0; n < 4; n++) {
        bf16x8 bf2 = *(const bf16x8*)(mp + p * 4096 + (n * 16 + fr) * 64 + kk * 32 + ko);
        acc[n] = __builtin_amdgcn_mfma_f32_16x16x32_bf16(af[kk], bf2, acc[n], 0, 0, 0);
      }
  unsigned short* op = o + ((size_t)(b * 2048 + l0)) * 1024 + h * 64;
  #pragma unroll
  for (int n = 0; n < 4; n++)
    #pragma unroll
    for (int i = 0; i < 4; i++)
      op[(size_t)(wv * 16 + (ln >> 4) * 4 + i) * 1024 + n * 16 + fr] = f2bf(acc[n][i]);
}

// ---------------------------------------------------------------------------
extern "C" void kernel_launch(void* const* d_in, const int* in_sizes, int n_in,
                              void* d_out, int out_size, void* d_ws, size_t ws_size,
                              hipStream_t stream) {
  const float* x     = (const float*)d_in[0];   // 4 x 2048 x 1024
  const float* Wqkv  = (const float*)d_in[1];   // 1024 x 3072
  const float* Wproj = (const float*)d_in[2];   // 1024 x 1024
  const float* bproj = (const float*)d_in[3];   // 1024
  float* out = (float*)d_out;                   // 8192 x 1024

  char* ws = (char*)d_ws;
  unsigned short* xb     = (unsigned short*)(ws);               // 16.78 MB
  unsigned short* MT     = (unsigned short*)(ws);               // 4 MB, aliases xb (dead after GEMM1)
  unsigned short* wqkvT  = (unsigned short*)(ws + 16777216);    //  6.29 MB
  unsigned short* wprojT = (unsigned short*)(ws + 23068672);    //  2.10 MB
  unsigned short* qkv    = (unsigned short*)(ws + 25165824);    // 50.33 MB
  unsigned short* ob     = (unsigned short*)(ws + 75497472);    // 16.78 MB

  // fused cast + weight transposes
  prep<<<12288, 256, 0, stream>>>(x, Wqkv, Wproj, xb, wqkvT, wprojT);

  // qkv = x @ W_qkv (8192x3072, bf16 out). Tile 256x128 -> grid 32x24 = 768
  // blocks = 3/CU x 256 CU exactly (48KB LDS, launch_bounds(256,3)).
  gemm_p<8, 4, 2, 4, 2, 3, 1><<<dim3(24, 32), 256, 0, stream>>>(
      xb, wqkvT, (void*)qkv, nullptr, 8192, 3072, 1024);

  // partial M^T per (b,h,half, j-quarter) — 512 blocks
  kv_outer<<<512, 256, 0, stream>>>(qkv, MT, 0.125f);
  // o = q @ sum_p M_p(other half)
  apply_q<<<2048, 256, 0, stream>>>(qkv, MT, ob);

  // out = o @ W_proj + b (fp32 out). Tile 128x64 -> grid 64x16 = 1024 blocks
  // = 4/CU x 256 CU exactly (24KB LDS, launch_bounds(256,4)).
  gemm_p<4, 2, 2, 2, 1, 4, 0><<<dim3(16, 64), 256, 0, stream>>>(
      ob, wprojT, (void*)out, bproj, 8192, 1024, 1024);
}

// Round 5
// 161.753 us; speedup vs baseline: 1.1078x; 1.1078x over previous
//
#include <hip/hip_runtime.h>
#include <stdint.h>

typedef __attribute__((ext_vector_type(8))) short  bf16x8;
typedef __attribute__((ext_vector_type(4))) short  short4v;
typedef __attribute__((ext_vector_type(4))) float  f32x4;
typedef __attribute__((ext_vector_type(4))) float  float4v;

__device__ __forceinline__ unsigned short f2bf(float f) {
  unsigned int u = __builtin_bit_cast(unsigned int, f);
  u += 0x7FFFu + ((u >> 16) & 1u);          // round-to-nearest-even
  return (unsigned short)(u >> 16);
}

__device__ __forceinline__ void async_ld16(const void* g, void* l) {
  __builtin_amdgcn_global_load_lds(
      (const __attribute__((address_space(1))) void*)g,
      (__attribute__((address_space(3))) void*)l,
      16, 0, 0);
}

// ----------------------------------------------------------- fused prep ----
__global__ __launch_bounds__(256) void prep(
    const float* __restrict__ x, const float* __restrict__ Wqkv,
    const float* __restrict__ Wproj,
    unsigned short* __restrict__ xb, unsigned short* __restrict__ wqkvT,
    unsigned short* __restrict__ wprojT) {
  __shared__ float tile[32][33];
  const int b = blockIdx.x, tid = threadIdx.x;
  if (b < 8192) {
    int i = b * 256 + tid;
    float4v v = *(const float4v*)(x + (size_t)i * 4);
    short4v o;
    o[0] = (short)f2bf(v[0]); o[1] = (short)f2bf(v[1]);
    o[2] = (short)f2bf(v[2]); o[3] = (short)f2bf(v[3]);
    *(short4v*)(xb + (size_t)i * 4) = o;
    return;
  }
  const float* in; unsigned short* out; int R, C, bx, by;
  if (b < 11264) { int t = b - 8192;  in = Wqkv;  out = wqkvT;  R = 1024; C = 3072; bx = t % 96; by = t / 96; }
  else           { int t = b - 11264; in = Wproj; out = wprojT; R = 1024; C = 1024; bx = t & 31; by = t >> 5; }
  const int tx = tid & 31, ty = tid >> 5;
  const int c0 = bx * 32, r0 = by * 32;
  #pragma unroll
  for (int rr = ty; rr < 32; rr += 8)
    tile[rr][tx] = in[(size_t)(r0 + rr) * C + c0 + tx];
  __syncthreads();
  #pragma unroll
  for (int cc = ty; cc < 32; cc += 8)
    out[(size_t)(c0 + cc) * R + r0 + tx] = f2bf(tile[tx][cc]);
}

// ----------------------------------------- m201-style 8-phase 256^2 GEMM ----
// C[M,N] = A[M,K]*BT[N,K]^T.  512 thr, 8 waves (2M x 4N), wave tile 128x64.
// LDS: 8 panel slots x 16KB (2 dbuf x {B0,B1,A0,A1}); panel = 128 rows x 64 bf16.
// Schedule: 1 panel staged per phase, 7-panel lookahead, vmcnt(6) once per
// K-tile (vmcnt(0) at NT-2).  Panels are ds_read ONCE (p0:16, p2:8 reads) and
// retained in regs, so each stage targets a slot last read in an earlier phase.
template<int BF16_OUT>
__global__ __launch_bounds__(512, 2) void gemm8t(
    const unsigned short* __restrict__ A,
    const unsigned short* __restrict__ BT,
    void* __restrict__ Cout, const float* __restrict__ bias,
    int M, int N, int K) {
  constexpr int PAN = 16384;                       // panel bytes
  __shared__ __align__(16) char lds[8 * PAN];      // 128 KiB
  const int tid = threadIdx.x;
  const int ln = tid & 63, w = tid >> 6;
  const int lr = ln & 15, lq = ln >> 4;
  const int wm = w >> 2, wn = w & 3;

  int wid = blockIdx.y * gridDim.x + blockIdx.x;
  const int nwg = gridDim.x * gridDim.y;
  { const int q = nwg >> 3; wid = (wid & 7) * q + (wid >> 3); }
  const int bm = (wid / gridDim.x) * 256, bn = (wid % gridDim.x) * 256;

  // ---- staging: linear LDS dest (thread tid -> panel byte tid*16, +8192),
  //      global source col pre-swizzled by dest row&7 ----
  const int srow = tid >> 3;
  const int csw = ((tid & 7) ^ (srow & 7)) * 8;
  const unsigned short* rB0 = BT + (size_t)(bn + srow) * K + csw;
  const unsigned short* rB1 = rB0 + (size_t)128 * K;
  const unsigned short* rA0 = A  + (size_t)(bm + srow) * K + csw;
  const unsigned short* rA1 = rA0 + (size_t)128 * K;
  const size_t rowL1 = (size_t)64 * K;
  char* ldst = lds + tid * 16;

#define STG(slot, src, t) do {                                               \
    async_ld16((src) + (size_t)(t) * 64,         ldst + (slot) * PAN);       \
    async_ld16((src) + (size_t)(t) * 64 + rowL1, ldst + (slot) * PAN + 8192);\
  } while (0)
#define SB() __builtin_amdgcn_sched_barrier(0)
#define BAR() __builtin_amdgcn_s_barrier()

  // ---- swizzled read offsets ----
  const int sw0 = ((0 + lq) ^ (lr & 7)) * 16;      // kstep 0
  const int sw1 = ((4 + lq) ^ (lr & 7)) * 16;      // kstep 1
  const char* Bbase = lds + ((wn & 1) * 64 + lr) * 128;
  const char* Abase = lds + lr * 128;

  bf16x8 a[4][2], b[4][2];
  f32x4 acc[8][4] = {};

#define READ_B(Bp)                                                           \
    _Pragma("unroll")                                                        \
    for (int nf = 0; nf < 4; ++nf) {                                         \
      const char* p_ = (Bp) + (nf >> 1) * 4096 + (nf & 1) * 2048;            \
      b[nf][0] = *(const bf16x8*)(p_ + sw0);                                 \
      b[nf][1] = *(const bf16x8*)(p_ + sw1);                                 \
    }
#define READ_A(Ap, mh)                                                       \
    _Pragma("unroll")                                                        \
    for (int fi = 0; fi < 4; ++fi) {                                         \
      const char* p_ = (Ap) + (mh) * 8192 + fi * 2048;                       \
      a[fi][0] = *(const bf16x8*)(p_ + sw0);                                 \
      a[fi][1] = *(const bf16x8*)(p_ + sw1);                                 \
    }
#define MFMA16(mh, nh)                                                       \
    __builtin_amdgcn_s_setprio(1);                                           \
    _Pragma("unroll")                                                        \
    for (int fi = 0; fi < 4; ++fi)                                           \
      _Pragma("unroll")                                                      \
      for (int bj = 0; bj < 2; ++bj) {                                       \
        f32x4 t_ = acc[(mh) * 4 + fi][(nh) * 2 + bj];                        \
        t_ = __builtin_amdgcn_mfma_f32_16x16x32_bf16(a[fi][0], b[(nh)*2+bj][0], t_, 0, 0, 0); \
        t_ = __builtin_amdgcn_mfma_f32_16x16x32_bf16(a[fi][1], b[(nh)*2+bj][1], t_, 0, 0, 0); \
        acc[(mh) * 4 + fi][(nh) * 2 + bj] = t_;                              \
      }                                                                      \
    __builtin_amdgcn_s_setprio(0);

  const int NT = K / 64;

  // ---- prologue: panels 0..6 (tile0 complete + tile1 B0,B1,A0) ----
  STG(0, rB0, 0); STG(1, rB1, 0); STG(2, rA0, 0); STG(3, rA1, 0);
  STG(4, rB0, 1); STG(5, rB1, 1); STG(6, rA0, 1);
  asm volatile("s_waitcnt vmcnt(6)" ::: "memory");
  SB(); BAR(); SB();

  for (int t = 0; t < NT; ++t) {
    const int par = (t & 1) * 4, opar = ((t + 1) & 1) * 4;
    const char* Ap = Abase + (size_t)(par + 2 + wm) * PAN;
    const char* Bp = Bbase + (size_t)(par + (wn >> 1)) * PAN;
    // ---- phase 0: quadrant (0,0) ----
    READ_B(Bp);
    READ_A(Ap, 0);
    if (t + 1 < NT) STG(opar + 3, rA1, t + 1);
    SB(); BAR(); SB();
    MFMA16(0, 0);
    SB(); BAR(); SB();
    // ---- phase 1: quadrant (0,1) ----
    if (t + 2 < NT) STG(par + 0, rB0, t + 2);
    SB(); BAR(); SB();
    MFMA16(0, 1);
    SB(); BAR(); SB();
    // ---- phase 2: quadrant (1,0) ----
    READ_A(Ap, 1);
    if (t + 2 < NT) STG(par + 1, rB1, t + 2);
    SB(); BAR(); SB();
    MFMA16(1, 0);
    SB(); BAR(); SB();
    // ---- phase 3: quadrant (1,1) ----
    if (t + 2 < NT) STG(par + 2, rA0, t + 2);
    SB(); BAR(); SB();
    MFMA16(1, 1);
    if (t < NT - 2)       asm volatile("s_waitcnt vmcnt(6)" ::: "memory");
    else if (t == NT - 2) asm volatile("s_waitcnt vmcnt(0)" ::: "memory");
    SB(); BAR(); SB();
  }
#undef STG
#undef READ_B
#undef READ_A
#undef MFMA16

  // ---- epilogue ----
  const int c0 = bn + wn * 64 + lr;
  if (BF16_OUT) {
    unsigned short* C = (unsigned short*)Cout;
    #pragma unroll
    for (int mf = 0; mf < 8; ++mf)
      #pragma unroll
      for (int i = 0; i < 4; ++i) {
        size_t r = (size_t)(bm + wm * 128 + (mf >> 2) * 64 + (mf & 3) * 16 + lq * 4 + i);
        #pragma unroll
        for (int nf = 0; nf < 4; ++nf)
          C[r * N + c0 + (nf >> 1) * 32 + (nf & 1) * 16] = f2bf(acc[mf][nf][i]);
      }
  } else {
    float* C = (float*)Cout;
    float bv[4];
    #pragma unroll
    for (int nf = 0; nf < 4; ++nf)
      bv[nf] = bias ? bias[c0 + (nf >> 1) * 32 + (nf & 1) * 16] : 0.f;
    #pragma unroll
    for (int mf = 0; mf < 8; ++mf)
      #pragma unroll
      for (int i = 0; i < 4; ++i) {
        size_t r = (size_t)(bm + wm * 128 + (mf >> 2) * 64 + (mf & 3) * 16 + lq * 4 + i);
        #pragma unroll
        for (int nf = 0; nf < 4; ++nf)
          C[r * N + c0 + (nf >> 1) * 32 + (nf & 1) * 16] = acc[mf][nf][i] + bv[nf];
      }
  }
}

// --------------------------------- partial M^T = scale*(k^T v)^T over j ----
__global__ __launch_bounds__(256) void kv_outer(
    const unsigned short* __restrict__ qkv,
    unsigned short* __restrict__ MT, float scale) {
  const int bid = blockIdx.x;
  const int p = bid & 3, unit = bid >> 2;
  const int b = unit >> 5, h = (unit >> 1) & 15, hf = unit & 1;
  const size_t base = ((size_t)(b * 2048 + hf * 1024)) * 3072 + h * 64;
  const unsigned short* kp = qkv + base + 1024;
  const unsigned short* vp = qkv + base + 2048;
  __shared__ __align__(16) unsigned short kT[64][136];
  __shared__ __align__(16) unsigned short vT[64][136];
  const int tid = threadIdx.x, wv = tid >> 6, ln = tid & 63;
  f32x4 acc[4] = {};
  const int e4 = (tid & 15) * 4;
  const int jr = tid >> 4;
  const int fr = ln & 15, ko = (ln >> 4) * 8;

  for (int j0 = p * 256; j0 < p * 256 + 256; j0 += 128) {
    __syncthreads();
    #pragma unroll
    for (int jj = 0; jj < 128; jj += 16) {
      int j = jj + jr;
      size_t go = (size_t)(j0 + j) * 3072 + e4;
      short4v k4 = *(const short4v*)(kp + go);
      short4v v4 = *(const short4v*)(vp + go);
      #pragma unroll
      for (int t = 0; t < 4; t++) {
        kT[e4 + t][j] = (unsigned short)k4[t];
        vT[e4 + t][j] = (unsigned short)v4[t];
      }
    }
    __syncthreads();
    #pragma unroll
    for (int kk = 0; kk < 128; kk += 32) {
      bf16x8 af = *(const bf16x8*)&kT[wv * 16 + fr][kk + ko];
      #pragma unroll
      for (int n = 0; n < 4; n++) {
        bf16x8 bf2 = *(const bf16x8*)&vT[n * 16 + fr][kk + ko];
        acc[n] = __builtin_amdgcn_mfma_f32_16x16x32_bf16(af, bf2, acc[n], 0, 0, 0);
      }
    }
  }
  unsigned short* outp = MT + (size_t)bid * 4096;       // [d][e], 64x64
  #pragma unroll
  for (int n = 0; n < 4; n++)
    #pragma unroll
    for (int i = 0; i < 4; i++) {
      int d = n * 16 + fr;
      int e = wv * 16 + (ln >> 4) * 4 + i;
      outp[d * 64 + e] = f2bf(acc[n][i] * scale);
    }
}

// ---------------------------------------------- o = q * sum_p M_p ----------
__global__ __launch_bounds__(256) void apply_q(
    const unsigned short* __restrict__ qkv,
    const unsigned short* __restrict__ MT,
    unsigned short* __restrict__ o) {
  const int bid = blockIdx.x;     // ((b*16+h)*2 + lhalf)*16 + lt
  const int lt = bid & 15, hf = (bid >> 4) & 1, h = (bid >> 5) & 15, b = bid >> 9;
  const int l0 = hf * 1024 + lt * 64;
  const unsigned short* qp = qkv + ((size_t)(b * 2048 + l0)) * 3072 + h * 64;
  const int unit_other = (b * 16 + h) * 2 + (1 - hf);
  const unsigned short* mp = MT + (size_t)unit_other * 4 * 4096;
  const int tid = threadIdx.x, wv = tid >> 6, ln = tid & 63;
  const int fr = ln & 15, ko = (ln >> 4) * 8;
  f32x4 acc[4] = {};
  bf16x8 af[2];
  #pragma unroll
  for (int kk = 0; kk < 2; kk++)
    af[kk] = *(const bf16x8*)(qp + (size_t)(wv * 16 + fr) * 3072 + kk * 32 + ko);
  #pragma unroll
  for (int p = 0; p < 4; ++p)
    #pragma unroll
    for (int kk = 0; kk < 2; kk++)
      #pragma unroll
      for (int n = 0; n < 4; n++) {
        bf16x8 bf2 = *(const bf16x8*)(mp + p * 4096 + (n * 16 + fr) * 64 + kk * 32 + ko);
        acc[n] = __builtin_amdgcn_mfma_f32_16x16x32_bf16(af[kk], bf2, acc[n], 0, 0, 0);
      }
  unsigned short* op = o + ((size_t)(b * 2048 + l0)) * 1024 + h * 64;
  #pragma unroll
  for (int n = 0; n < 4; n++)
    #pragma unroll
    for (int i = 0; i < 4; i++)
      op[(size_t)(wv * 16 + (ln >> 4) * 4 + i) * 1024 + n * 16 + fr] = f2bf(acc[n][i]);
}

// ---------------------------------------------------------------------------
extern "C" void kernel_launch(void* const* d_in, const int* in_sizes, int n_in,
                              void* d_out, int out_size, void* d_ws, size_t ws_size,
                              hipStream_t stream) {
  const float* x     = (const float*)d_in[0];   // 4 x 2048 x 1024
  const float* Wqkv  = (const float*)d_in[1];   // 1024 x 3072
  const float* Wproj = (const float*)d_in[2];   // 1024 x 1024
  const float* bproj = (const float*)d_in[3];   // 1024
  float* out = (float*)d_out;                   // 8192 x 1024

  char* ws = (char*)d_ws;
  unsigned short* xb     = (unsigned short*)(ws);               // 16.78 MB
  unsigned short* MT     = (unsigned short*)(ws);               // 4 MB, aliases xb (dead after GEMM1)
  unsigned short* wqkvT  = (unsigned short*)(ws + 16777216);    //  6.29 MB
  unsigned short* wprojT = (unsigned short*)(ws + 23068672);    //  2.10 MB
  unsigned short* qkv    = (unsigned short*)(ws + 25165824);    // 50.33 MB
  unsigned short* ob     = (unsigned short*)(ws + 75497472);    // 16.78 MB

  // fused cast + weight transposes
  prep<<<12288, 256, 0, stream>>>(x, Wqkv, Wproj, xb, wqkvT, wprojT);

  // qkv = x @ W_qkv (8192x3072, bf16 out). 256^2 tiles -> grid 12x32 = 384.
  gemm8t<1><<<dim3(12, 32), 512, 0, stream>>>(xb, wqkvT, (void*)qkv, nullptr,
                                              8192, 3072, 1024);

  // partial M^T per (b,h,half, j-quarter) — 512 blocks
  kv_outer<<<512, 256, 0, stream>>>(qkv, MT, 0.125f);
  // o = q @ sum_p M_p(other half)
  apply_q<<<2048, 256, 0, stream>>>(qkv, MT, ob);

  // out = o @ W_proj + b (fp32 out). 256^2 tiles -> grid 4x32 = 128.
  gemm8t<0><<<dim3(4, 32), 512, 0, stream>>>(ob, wprojT, (void*)out, bproj,
                                             8192, 1024, 1024);
}

// Round 6
// 144.514 us; speedup vs baseline: 1.2399x; 1.1193x over previous
//
#include <hip/hip_runtime.h>
#include <stdint.h>

typedef __attribute__((ext_vector_type(8))) short  bf16x8;
typedef __attribute__((ext_vector_type(4))) short  short4v;
typedef __attribute__((ext_vector_type(4))) float  f32x4;
typedef __attribute__((ext_vector_type(4))) float  float4v;

__device__ __forceinline__ unsigned short f2bf(float f) {
  unsigned int u = __builtin_bit_cast(unsigned int, f);
  u += 0x7FFFu + ((u >> 16) & 1u);          // round-to-nearest-even
  return (unsigned short)(u >> 16);
}

__device__ __forceinline__ void async_ld16(const void* g, void* l) {
  __builtin_amdgcn_global_load_lds(
      (const __attribute__((address_space(1))) void*)g,
      (__attribute__((address_space(3))) void*)l,
      16, 0, 0);
}

#define SB()  __builtin_amdgcn_sched_barrier(0)
#define BAR() __builtin_amdgcn_s_barrier()

// ----------------------------------------------------------- fused prep ----
__global__ __launch_bounds__(256) void prep(
    const float* __restrict__ x, const float* __restrict__ Wqkv,
    const float* __restrict__ Wproj,
    unsigned short* __restrict__ xb, unsigned short* __restrict__ wqkvT,
    unsigned short* __restrict__ wprojT) {
  __shared__ float tile[32][33];
  const int b = blockIdx.x, tid = threadIdx.x;
  if (b < 8192) {
    int i = b * 256 + tid;
    float4v v = *(const float4v*)(x + (size_t)i * 4);
    short4v o;
    o[0] = (short)f2bf(v[0]); o[1] = (short)f2bf(v[1]);
    o[2] = (short)f2bf(v[2]); o[3] = (short)f2bf(v[3]);
    *(short4v*)(xb + (size_t)i * 4) = o;
    return;
  }
  const float* in; unsigned short* out; int R, C, bx, by;
  if (b < 11264) { int t = b - 8192;  in = Wqkv;  out = wqkvT;  R = 1024; C = 3072; bx = t % 96; by = t / 96; }
  else           { int t = b - 11264; in = Wproj; out = wprojT; R = 1024; C = 1024; bx = t & 31; by = t >> 5; }
  const int tx = tid & 31, ty = tid >> 5;
  const int c0 = bx * 32, r0 = by * 32;
  #pragma unroll
  for (int rr = ty; rr < 32; rr += 8)
    tile[rr][tx] = in[(size_t)(r0 + rr) * C + c0 + tx];
  __syncthreads();
  #pragma unroll
  for (int cc = ty; cc < 32; cc += 8)
    out[(size_t)(c0 + cc) * R + r0 + tx] = f2bf(tile[tx][cc]);
}

// ----------------------------------------- 8-phase 256^2 GEMM (unchanged) ----
// C[M,N] = A*BT^T.  512 thr, 8 waves (2M x 4N), wave 128x64, BK=64.
// 8 panel slots x 16KB; 7-panel lookahead; vmcnt(6) once per K-tile.
template<int BF16_OUT>
__global__ __launch_bounds__(512, 2) void gemm8t(
    const unsigned short* __restrict__ A,
    const unsigned short* __restrict__ BT,
    void* __restrict__ Cout, const float* __restrict__ bias,
    int ldc, int K) {
  constexpr int PAN = 16384;
  __shared__ __align__(16) char lds[8 * PAN];      // 128 KiB
  const int tid = threadIdx.x;
  const int ln = tid & 63, w = tid >> 6;
  const int lr = ln & 15, lq = ln >> 4;
  const int wm = w >> 2, wn = w & 3;

  int wid = blockIdx.y * gridDim.x + blockIdx.x;
  const int nwg = gridDim.x * gridDim.y;
  { const int q = nwg >> 3; wid = (wid & 7) * q + (wid >> 3); }
  const int bm = (wid / gridDim.x) * 256, bn = (wid % gridDim.x) * 256;

  const int srow = tid >> 3;
  const int csw = ((tid & 7) ^ (srow & 7)) * 8;
  const unsigned short* rB0 = BT + (size_t)(bn + srow) * K + csw;
  const unsigned short* rB1 = rB0 + (size_t)128 * K;
  const unsigned short* rA0 = A  + (size_t)(bm + srow) * K + csw;
  const unsigned short* rA1 = rA0 + (size_t)128 * K;
  const size_t rowL1 = (size_t)64 * K;
  char* ldst = lds + tid * 16;

#define STG(slot, src, t) do {                                               \
    async_ld16((src) + (size_t)(t) * 64,         ldst + (slot) * PAN);       \
    async_ld16((src) + (size_t)(t) * 64 + rowL1, ldst + (slot) * PAN + 8192);\
  } while (0)

  const int sw0 = ((0 + lq) ^ (lr & 7)) * 16;
  const int sw1 = ((4 + lq) ^ (lr & 7)) * 16;
  const char* Bbase = lds + ((wn & 1) * 64 + lr) * 128;
  const char* Abase = lds + lr * 128;

  bf16x8 a[4][2], b[4][2];
  f32x4 acc[8][4] = {};

#define READ_B(Bp)                                                           \
    _Pragma("unroll")                                                        \
    for (int nf = 0; nf < 4; ++nf) {                                         \
      const char* p_ = (Bp) + (nf >> 1) * 4096 + (nf & 1) * 2048;            \
      b[nf][0] = *(const bf16x8*)(p_ + sw0);                                 \
      b[nf][1] = *(const bf16x8*)(p_ + sw1);                                 \
    }
#define READ_A(Ap, mh)                                                       \
    _Pragma("unroll")                                                        \
    for (int fi = 0; fi < 4; ++fi) {                                         \
      const char* p_ = (Ap) + (mh) * 8192 + fi * 2048;                       \
      a[fi][0] = *(const bf16x8*)(p_ + sw0);                                 \
      a[fi][1] = *(const bf16x8*)(p_ + sw1);                                 \
    }
#define MFMA16(mh, nh)                                                       \
    __builtin_amdgcn_s_setprio(1);                                           \
    _Pragma("unroll")                                                        \
    for (int fi = 0; fi < 4; ++fi)                                           \
      _Pragma("unroll")                                                      \
      for (int bj = 0; bj < 2; ++bj) {                                       \
        f32x4 t_ = acc[(mh) * 4 + fi][(nh) * 2 + bj];                        \
        t_ = __builtin_amdgcn_mfma_f32_16x16x32_bf16(a[fi][0], b[(nh)*2+bj][0], t_, 0, 0, 0); \
        t_ = __builtin_amdgcn_mfma_f32_16x16x32_bf16(a[fi][1], b[(nh)*2+bj][1], t_, 0, 0, 0); \
        acc[(mh) * 4 + fi][(nh) * 2 + bj] = t_;                              \
      }                                                                      \
    __builtin_amdgcn_s_setprio(0);

  const int NT = K / 64;

  STG(0, rB0, 0); STG(1, rB1, 0); STG(2, rA0, 0); STG(3, rA1, 0);
  STG(4, rB0, 1); STG(5, rB1, 1); STG(6, rA0, 1);
  asm volatile("s_waitcnt vmcnt(6)" ::: "memory");
  SB(); BAR(); SB();

  for (int t = 0; t < NT; ++t) {
    const int par = (t & 1) * 4, opar = ((t + 1) & 1) * 4;
    const char* Ap = Abase + (size_t)(par + 2 + wm) * PAN;
    const char* Bp = Bbase + (size_t)(par + (wn >> 1)) * PAN;
    READ_B(Bp);
    READ_A(Ap, 0);
    if (t + 1 < NT) STG(opar + 3, rA1, t + 1);
    SB(); BAR(); SB();
    MFMA16(0, 0);
    SB(); BAR(); SB();
    if (t + 2 < NT) STG(par + 0, rB0, t + 2);
    SB(); BAR(); SB();
    MFMA16(0, 1);
    SB(); BAR(); SB();
    READ_A(Ap, 1);
    if (t + 2 < NT) STG(par + 1, rB1, t + 2);
    SB(); BAR(); SB();
    MFMA16(1, 0);
    SB(); BAR(); SB();
    if (t + 2 < NT) STG(par + 2, rA0, t + 2);
    SB(); BAR(); SB();
    MFMA16(1, 1);
    if (t < NT - 2)       asm volatile("s_waitcnt vmcnt(6)" ::: "memory");
    else if (t == NT - 2) asm volatile("s_waitcnt vmcnt(0)" ::: "memory");
    SB(); BAR(); SB();
  }
#undef STG
#undef READ_B
#undef READ_A
#undef MFMA16

  const int c0 = bn + wn * 64 + lr;
  if (BF16_OUT) {
    unsigned short* C = (unsigned short*)Cout;
    #pragma unroll
    for (int mf = 0; mf < 8; ++mf)
      #pragma unroll
      for (int i = 0; i < 4; ++i) {
        size_t r = (size_t)(bm + wm * 128 + (mf >> 2) * 64 + (mf & 3) * 16 + lq * 4 + i);
        #pragma unroll
        for (int nf = 0; nf < 4; ++nf)
          C[r * ldc + c0 + (nf >> 1) * 32 + (nf & 1) * 16] = f2bf(acc[mf][nf][i]);
      }
  } else {
    float* C = (float*)Cout;
    float bv[4];
    #pragma unroll
    for (int nf = 0; nf < 4; ++nf)
      bv[nf] = bias ? bias[c0 + (nf >> 1) * 32 + (nf & 1) * 16] : 0.f;
    #pragma unroll
    for (int mf = 0; mf < 8; ++mf)
      #pragma unroll
      for (int i = 0; i < 4; ++i) {
        size_t r = (size_t)(bm + wm * 128 + (mf >> 2) * 64 + (mf & 3) * 16 + lq * 4 + i);
        #pragma unroll
        for (int nf = 0; nf < 4; ++nf)
          C[r * ldc + c0 + (nf >> 1) * 32 + (nf & 1) * 16] = acc[mf][nf][i] + bv[nf];
      }
  }
}

// -------------------------------- 128x256-tile variant (exact 256 grids) ----
// Same machinery; panels/buf = {B0,B1,A}; 6 slots = 96KB; wave tile 64x64.
// Ledger: prologue stages t0,t1 (12 ld) vmcnt(6); per tile: ph0/ph1 read+MFMA;
// tile-end stages t+2 (6 ld) then vmcnt(6) [vmcnt(0) at NT-2].
template<int BF16_OUT>
__global__ __launch_bounds__(512, 1) void gemm128(
    const unsigned short* __restrict__ A,
    const unsigned short* __restrict__ BT,
    void* __restrict__ Cout, const float* __restrict__ bias,
    int ldc, int K) {
  constexpr int PAN = 16384;
  __shared__ __align__(16) char lds[6 * PAN];      // 96 KiB
  const int tid = threadIdx.x;
  const int ln = tid & 63, w = tid >> 6;
  const int lr = ln & 15, lq = ln >> 4;
  const int wm = w >> 2, wn = w & 3;

  int wid = blockIdx.y * gridDim.x + blockIdx.x;
  const int nwg = gridDim.x * gridDim.y;
  { const int q = nwg >> 3; wid = (wid & 7) * q + (wid >> 3); }
  const int bm = (wid / gridDim.x) * 128, bn = (wid % gridDim.x) * 256;

  const int srow = tid >> 3;
  const int csw = ((tid & 7) ^ (srow & 7)) * 8;
  const unsigned short* rB0 = BT + (size_t)(bn + srow) * K + csw;
  const unsigned short* rB1 = rB0 + (size_t)128 * K;
  const unsigned short* rA0 = A  + (size_t)(bm + srow) * K + csw;
  const size_t rowL1 = (size_t)64 * K;
  char* ldst = lds + tid * 16;

#define STG(slot, src, t) do {                                               \
    async_ld16((src) + (size_t)(t) * 64,         ldst + (slot) * PAN);       \
    async_ld16((src) + (size_t)(t) * 64 + rowL1, ldst + (slot) * PAN + 8192);\
  } while (0)

  const int sw0 = ((0 + lq) ^ (lr & 7)) * 16;
  const int sw1 = ((4 + lq) ^ (lr & 7)) * 16;
  const char* Arow = lds + (wm * 64 + lr) * 128;              // + slot*PAN + fi*2048
  const char* Brow = lds + ((wn & 1) * 64 + lr) * 128;        // + slot*PAN + nf*2048

  bf16x8 a[4], b[4];
  f32x4 acc[4][4] = {};

#define RD(ph_sw, Ap, Bp)                                                    \
    _Pragma("unroll")                                                        \
    for (int nf = 0; nf < 4; ++nf) b[nf] = *(const bf16x8*)((Bp) + nf * 2048 + (ph_sw)); \
    _Pragma("unroll")                                                        \
    for (int fi = 0; fi < 4; ++fi) a[fi] = *(const bf16x8*)((Ap) + fi * 2048 + (ph_sw));
#define MM16()                                                               \
    __builtin_amdgcn_s_setprio(1);                                           \
    _Pragma("unroll")                                                        \
    for (int fi = 0; fi < 4; ++fi)                                           \
      _Pragma("unroll")                                                      \
      for (int nf = 0; nf < 4; ++nf)                                         \
        acc[fi][nf] = __builtin_amdgcn_mfma_f32_16x16x32_bf16(a[fi], b[nf], acc[fi][nf], 0, 0, 0); \
    __builtin_amdgcn_s_setprio(0);

  STG(0, rB0, 0); STG(1, rB1, 0); STG(2, rA0, 0);
  STG(3, rB0, 1); STG(4, rB1, 1); STG(5, rA0, 1);
  asm volatile("s_waitcnt vmcnt(6)" ::: "memory");
  SB(); BAR(); SB();

  const int NT = K / 64;
  for (int t = 0; t < NT; ++t) {
    const int par = (t & 1) * 3;
    const char* Ap = Arow + (par + 2) * PAN;
    const char* Bp = Brow + (par + (wn >> 1)) * PAN;
    // phase 0 (k 0..31)
    RD(sw0, Ap, Bp);
    SB(); BAR(); SB();
    MM16();
    SB(); BAR(); SB();
    // phase 1 (k 32..63)
    RD(sw1, Ap, Bp);
    SB(); BAR(); SB();
    MM16();
    // tile end: stage t+2 into par slots (all par reads retired pre-MFMA)
    if (t + 2 < NT) {
      STG(par + 0, rB0, t + 2); STG(par + 1, rB1, t + 2); STG(par + 2, rA0, t + 2);
      asm volatile("s_waitcnt vmcnt(6)" ::: "memory");
    } else if (t == NT - 2) {
      asm volatile("s_waitcnt vmcnt(0)" ::: "memory");
    }
    SB(); BAR(); SB();
  }
#undef STG
#undef RD
#undef MM16

  const int c0 = bn + wn * 64 + lr;
  if (BF16_OUT) {
    unsigned short* C = (unsigned short*)Cout;
    #pragma unroll
    for (int fi = 0; fi < 4; ++fi)
      #pragma unroll
      for (int i = 0; i < 4; ++i) {
        size_t r = (size_t)(bm + wm * 64 + fi * 16 + lq * 4 + i);
        #pragma unroll
        for (int nf = 0; nf < 4; ++nf)
          C[r * ldc + c0 + (nf >> 1) * 32 + (nf & 1) * 16] = f2bf(acc[fi][nf][i]);
      }
  } else {
    float* C = (float*)Cout;
    float bv[4];
    #pragma unroll
    for (int nf = 0; nf < 4; ++nf)
      bv[nf] = bias ? bias[c0 + (nf >> 1) * 32 + (nf & 1) * 16] : 0.f;
    #pragma unroll
    for (int fi = 0; fi < 4; ++fi)
      #pragma unroll
      for (int i = 0; i < 4; ++i) {
        size_t r = (size_t)(bm + wm * 64 + fi * 16 + lq * 4 + i);
        #pragma unroll
        for (int nf = 0; nf < 4; ++nf)
          C[r * ldc + c0 + (nf >> 1) * 32 + (nf & 1) * 16] = acc[fi][nf][i] + bv[nf];
      }
  }
}

// --------------------------------- partial M^T = scale*(k^T v)^T over j ----
__global__ __launch_bounds__(256) void kv_outer(
    const unsigned short* __restrict__ qkv,
    unsigned short* __restrict__ MT, float scale) {
  const int bid = blockIdx.x;
  const int p = bid & 3, unit = bid >> 2;
  const int b = unit >> 5, h = (unit >> 1) & 15, hf = unit & 1;
  const size_t base = ((size_t)(b * 2048 + hf * 1024)) * 3072 + h * 64;
  const unsigned short* kp = qkv + base + 1024;
  const unsigned short* vp = qkv + base + 2048;
  __shared__ __align__(16) unsigned short kT[64][136];
  __shared__ __align__(16) unsigned short vT[64][136];
  const int tid = threadIdx.x, wv = tid >> 6, ln = tid & 63;
  f32x4 acc[4] = {};
  const int e4 = (tid & 15) * 4;
  const int jr = tid >> 4;
  const int fr = ln & 15, ko = (ln >> 4) * 8;

  for (int j0 = p * 256; j0 < p * 256 + 256; j0 += 128) {
    __syncthreads();
    #pragma unroll
    for (int jj = 0; jj < 128; jj += 16) {
      int j = jj + jr;
      size_t go = (size_t)(j0 + j) * 3072 + e4;
      short4v k4 = *(const short4v*)(kp + go);
      short4v v4 = *(const short4v*)(vp + go);
      #pragma unroll
      for (int t = 0; t < 4; t++) {
        kT[e4 + t][j] = (unsigned short)k4[t];
        vT[e4 + t][j] = (unsigned short)v4[t];
      }
    }
    __syncthreads();
    #pragma unroll
    for (int kk = 0; kk < 128; kk += 32) {
      bf16x8 af = *(const bf16x8*)&kT[wv * 16 + fr][kk + ko];
      #pragma unroll
      for (int n = 0; n < 4; n++) {
        bf16x8 bf2 = *(const bf16x8*)&vT[n * 16 + fr][kk + ko];
        acc[n] = __builtin_amdgcn_mfma_f32_16x16x32_bf16(af, bf2, acc[n], 0, 0, 0);
      }
    }
  }
  unsigned short* outp = MT + (size_t)bid * 4096;       // [d][e], 64x64
  #pragma unroll
  for (int n = 0; n < 4; n++)
    #pragma unroll
    for (int i = 0; i < 4; i++) {
      int d = n * 16 + fr;
      int e = wv * 16 + (ln >> 4) * 4 + i;
      outp[d * 64 + e] = f2bf(acc[n][i] * scale);
    }
}

// ---------------------------------------------- o = q * sum_p M_p ----------
__global__ __launch_bounds__(256) void apply_q(
    const unsigned short* __restrict__ qkv,
    const unsigned short* __restrict__ MT,
    unsigned short* __restrict__ o) {
  const int bid = blockIdx.x;     // ((b*16+h)*2 + lhalf)*16 + lt
  const int lt = bid & 15, hf = (bid >> 4) & 1, h = (bid >> 5) & 15, b = bid >> 9;
  const int l0 = hf * 1024 + lt * 64;
  const unsigned short* qp = qkv + ((size_t)(b * 2048 + l0)) * 3072 + h * 64;
  const int unit_other = (b * 16 + h) * 2 + (1 - hf);
  const unsigned short* mp = MT + (size_t)unit_other * 4 * 4096;
  const int tid = threadIdx.x, wv = tid >> 6, ln = tid & 63;
  const int fr = ln & 15, ko = (ln >> 4) * 8;
  f32x4 acc[4] = {};
  bf16x8 af[2];
  #pragma unroll
  for (int kk = 0; kk < 2; kk++)
    af[kk] = *(const bf16x8*)(qp + (size_t)(wv * 16 + fr) * 3072 + kk * 32 + ko);
  #pragma unroll
  for (int p = 0; p < 4; ++p)
    #pragma unroll
    for (int kk = 0; kk < 2; kk++)
      #pragma unroll
      for (int n = 0; n < 4; n++) {
        bf16x8 bf2 = *(const bf16x8*)(mp + p * 4096 + (n * 16 + fr) * 64 + kk * 32 + ko);
        acc[n] = __builtin_amdgcn_mfma_f32_16x16x32_bf16(af[kk], bf2, acc[n], 0, 0, 0);
      }
  unsigned short* op = o + ((size_t)(b * 2048 + l0)) * 1024 + h * 64;
  #pragma unroll
  for (int n = 0; n < 4; n++)
    #pragma unroll
    for (int i = 0; i < 4; i++)
      op[(size_t)(wv * 16 + (ln >> 4) * 4 + i) * 1024 + n * 16 + fr] = f2bf(acc[n][i]);
}

// ---------------------------------------------------------------------------
extern "C" void kernel_launch(void* const* d_in, const int* in_sizes, int n_in,
                              void* d_out, int out_size, void* d_ws, size_t ws_size,
                              hipStream_t stream) {
  const float* x     = (const float*)d_in[0];   // 4 x 2048 x 1024
  const float* Wqkv  = (const float*)d_in[1];   // 1024 x 3072
  const float* Wproj = (const float*)d_in[2];   // 1024 x 1024
  const float* bproj = (const float*)d_in[3];   // 1024
  float* out = (float*)d_out;                   // 8192 x 1024

  char* ws = (char*)d_ws;
  unsigned short* xb     = (unsigned short*)(ws);               // 16.78 MB
  unsigned short* MT     = (unsigned short*)(ws);               // 4 MB, aliases xb (dead after v-GEMM)
  unsigned short* wqkvT  = (unsigned short*)(ws + 16777216);    //  6.29 MB
  unsigned short* wprojT = (unsigned short*)(ws + 23068672);    //  2.10 MB
  unsigned short* qkv    = (unsigned short*)(ws + 25165824);    // 50.33 MB
  unsigned short* ob     = (unsigned short*)(ws + 75497472);    // 16.78 MB

  // fused cast + weight transposes
  prep<<<12288, 256, 0, stream>>>(x, Wqkv, Wproj, xb, wqkvT, wprojT);

  // qk = x @ W_qkv[:, :2048] -> qkv cols 0..2047.  grid 8x32 = 256 exact.
  gemm8t<1><<<dim3(8, 32), 512, 0, stream>>>(xb, wqkvT, (void*)qkv, nullptr,
                                             3072, 1024);
  // v = x @ W_qkv[:, 2048:] -> qkv cols 2048..3071.  grid 4x64 = 256 exact.
  gemm128<1><<<dim3(4, 64), 512, 0, stream>>>(xb, wqkvT + (size_t)2048 * 1024,
                                              (void*)(qkv + 2048), nullptr,
                                              3072, 1024);

  // partial M^T per (b,h,half, j-quarter) — 512 blocks
  kv_outer<<<512, 256, 0, stream>>>(qkv, MT, 0.125f);
  // o = q @ sum_p M_p(other half)
  apply_q<<<2048, 256, 0, stream>>>(qkv, MT, ob);

  // out = o @ W_proj + b (fp32).  grid 4x64 = 256 exact.
  gemm128<0><<<dim3(4, 64), 512, 0, stream>>>(ob, wprojT, (void*)out, bproj,
                                              1024, 1024);
}

// Round 7
// 125.395 us; speedup vs baseline: 1.4289x; 1.1525x over previous
//
#include <hip/hip_runtime.h>
#include <stdint.h>

typedef __attribute__((ext_vector_type(8))) short  bf16x8;
typedef __attribute__((ext_vector_type(4))) short  short4v;
typedef __attribute__((ext_vector_type(4))) float  f32x4;
typedef __attribute__((ext_vector_type(4))) float  float4v;

__device__ __forceinline__ unsigned short f2bf(float f) {
  unsigned int u = __builtin_bit_cast(unsigned int, f);
  u += 0x7FFFu + ((u >> 16) & 1u);          // round-to-nearest-even
  return (unsigned short)(u >> 16);
}
__device__ __forceinline__ float bf2f(unsigned short u) {
  return __builtin_bit_cast(float, (unsigned int)u << 16);
}

__device__ __forceinline__ void async_ld16(const void* g, void* l) {
  __builtin_amdgcn_global_load_lds(
      (const __attribute__((address_space(1))) void*)g,
      (__attribute__((address_space(3))) void*)l,
      16, 0, 0);
}

#define SB()  __builtin_amdgcn_sched_barrier(0)
#define BAR() __builtin_amdgcn_s_barrier()

// ----------------------------------------------------------- fused prep ----
__global__ __launch_bounds__(256) void prep(
    const float* __restrict__ x, const float* __restrict__ Wqkv,
    const float* __restrict__ Wproj,
    unsigned short* __restrict__ xb, unsigned short* __restrict__ wqkvT,
    unsigned short* __restrict__ wprojT) {
  __shared__ float tile[32][33];
  const int b = blockIdx.x, tid = threadIdx.x;
  if (b < 8192) {
    int i = b * 256 + tid;
    float4v v = *(const float4v*)(x + (size_t)i * 4);
    short4v o;
    o[0] = (short)f2bf(v[0]); o[1] = (short)f2bf(v[1]);
    o[2] = (short)f2bf(v[2]); o[3] = (short)f2bf(v[3]);
    *(short4v*)(xb + (size_t)i * 4) = o;
    return;
  }
  const float* in; unsigned short* out; int R, C, bx, by;
  if (b < 11264) { int t = b - 8192;  in = Wqkv;  out = wqkvT;  R = 1024; C = 3072; bx = t % 96; by = t / 96; }
  else           { int t = b - 11264; in = Wproj; out = wprojT; R = 1024; C = 1024; bx = t & 31; by = t >> 5; }
  const int tx = tid & 31, ty = tid >> 5;
  const int c0 = bx * 32, r0 = by * 32;
  #pragma unroll
  for (int rr = ty; rr < 32; rr += 8)
    tile[rr][tx] = in[(size_t)(r0 + rr) * C + c0 + tx];
  __syncthreads();
  #pragma unroll
  for (int cc = ty; cc < 32; cc += 8)
    out[(size_t)(c0 + cc) * R + r0 + tx] = f2bf(tile[tx][cc]);
}

// ----------------------------------------- 8-phase 256^2 GEMM (spread-read) ----
// C[M,N] = A*BT^T.  512 thr, 8 waves (2M x 4N), wave 128x64, BK=64.
// Reads spread 12/4/8/0 per phase (per-quadrant); staging 1 panel/phase:
// ph0: A0(t+1)->opar+2, ph1: A1(t+1)->opar+3, ph2: B0(t+2)->par+0,
// ph3: B1(t+2)->par+1.  End-of-tile vmcnt(4) [queue: A(t+1)x4 + B(t+2)x4].
template<int BF16_OUT>
__global__ __launch_bounds__(512, 2) void gemm8t(
    const unsigned short* __restrict__ A,
    const unsigned short* __restrict__ BT,
    void* __restrict__ Cout, const float* __restrict__ bias,
    int ldc, int K) {
  constexpr int PAN = 16384;
  __shared__ __align__(16) char lds[8 * PAN];      // 128 KiB
  const int tid = threadIdx.x;
  const int ln = tid & 63, w = tid >> 6;
  const int lr = ln & 15, lq = ln >> 4;
  const int wm = w >> 2, wn = w & 3;

  int wid = blockIdx.y * gridDim.x + blockIdx.x;
  const int nwg = gridDim.x * gridDim.y;
  { const int q = nwg >> 3; wid = (wid & 7) * q + (wid >> 3); }
  const int bm = (wid / gridDim.x) * 256, bn = (wid % gridDim.x) * 256;

  const int srow = tid >> 3;
  const int csw = ((tid & 7) ^ (srow & 7)) * 8;
  const unsigned short* rB0 = BT + (size_t)(bn + srow) * K + csw;
  const unsigned short* rB1 = rB0 + (size_t)128 * K;
  const unsigned short* rA0 = A  + (size_t)(bm + srow) * K + csw;
  const unsigned short* rA1 = rA0 + (size_t)128 * K;
  const size_t rowL1 = (size_t)64 * K;
  char* ldst = lds + tid * 16;

#define STG(slot, src, t) do {                                               \
    async_ld16((src) + (size_t)(t) * 64,         ldst + (slot) * PAN);       \
    async_ld16((src) + (size_t)(t) * 64 + rowL1, ldst + (slot) * PAN + 8192);\
  } while (0)

  const int sw0 = ((0 + lq) ^ (lr & 7)) * 16;
  const int sw1 = ((4 + lq) ^ (lr & 7)) * 16;
  const char* Bbase = lds + ((wn & 1) * 64 + lr) * 128;
  const char* Abase = lds + lr * 128;

  bf16x8 a[4][2], b[4][2];
  f32x4 acc[8][4] = {};

#define READ_B2(Bp, nh)                                                      \
    _Pragma("unroll")                                                        \
    for (int bj = 0; bj < 2; ++bj) {                                         \
      const char* p_ = (Bp) + (nh) * 4096 + bj * 2048;                       \
      b[(nh) * 2 + bj][0] = *(const bf16x8*)(p_ + sw0);                      \
      b[(nh) * 2 + bj][1] = *(const bf16x8*)(p_ + sw1);                      \
    }
#define READ_A(Ap, mh)                                                       \
    _Pragma("unroll")                                                        \
    for (int fi = 0; fi < 4; ++fi) {                                         \
      const char* p_ = (Ap) + fi * 2048;                                     \
      a[fi][0] = *(const bf16x8*)(p_ + sw0);                                 \
      a[fi][1] = *(const bf16x8*)(p_ + sw1);                                 \
    }
#define MFMA16(mh, nh)                                                       \
    __builtin_amdgcn_s_setprio(1);                                           \
    _Pragma("unroll")                                                        \
    for (int fi = 0; fi < 4; ++fi)                                           \
      _Pragma("unroll")                                                      \
      for (int bj = 0; bj < 2; ++bj) {                                       \
        f32x4 t_ = acc[(mh) * 4 + fi][(nh) * 2 + bj];                        \
        t_ = __builtin_amdgcn_mfma_f32_16x16x32_bf16(a[fi][0], b[(nh)*2+bj][0], t_, 0, 0, 0); \
        t_ = __builtin_amdgcn_mfma_f32_16x16x32_bf16(a[fi][1], b[(nh)*2+bj][1], t_, 0, 0, 0); \
        acc[(mh) * 4 + fi][(nh) * 2 + bj] = t_;                              \
      }                                                                      \
    __builtin_amdgcn_s_setprio(0);

  const int NT = K / 64;

  // prologue: tile0 complete (slots 0..3) + tile1 B panels (slots 4,5)
  STG(0, rB0, 0); STG(1, rB1, 0); STG(2, rA0, 0); STG(3, rA1, 0);
  STG(4, rB0, 1); STG(5, rB1, 1);
  asm volatile("s_waitcnt vmcnt(4)" ::: "memory");
  SB(); BAR(); SB();

  for (int t = 0; t < NT; ++t) {
    const int par = (t & 1) * 4, opar = ((t + 1) & 1) * 4;
    const char* Ap = Abase + (size_t)(par + 2 + wm) * PAN;
    const char* Bp = Bbase + (size_t)(par + (wn >> 1)) * PAN;
    // ---- phase 0: reads B-half0 (4) + A-mh0 (8); stage A0(t+1) ----
    READ_B2(Bp, 0);
    READ_A(Ap, 0);
    if (t + 1 < NT) STG(opar + 2, rA0, t + 1);
    SB(); BAR();
    asm volatile("s_waitcnt lgkmcnt(0)" ::: "memory");
    SB();
    MFMA16(0, 0);
    SB(); BAR(); SB();
    // ---- phase 1: reads B-half1 (4); stage A1(t+1) ----
    READ_B2(Bp, 1);
    if (t + 1 < NT) STG(opar + 3, rA1, t + 1);
    SB(); BAR();
    asm volatile("s_waitcnt lgkmcnt(0)" ::: "memory");
    SB();
    MFMA16(0, 1);
    SB(); BAR(); SB();
    // ---- phase 2: reads A-mh1 (8); stage B0(t+2) ----
    READ_A(Ap + 8192, 1);
    if (t + 2 < NT) STG(par + 0, rB0, t + 2);
    SB(); BAR();
    asm volatile("s_waitcnt lgkmcnt(0)" ::: "memory");
    SB();
    MFMA16(1, 0);
    SB(); BAR(); SB();
    // ---- phase 3: stage B1(t+2); MFMA; counted wait ----
    if (t + 2 < NT) STG(par + 1, rB1, t + 2);
    SB(); BAR(); SB();
    MFMA16(1, 1);
    if (t < NT - 2)       asm volatile("s_waitcnt vmcnt(4)" ::: "memory");
    else if (t == NT - 2) asm volatile("s_waitcnt vmcnt(0)" ::: "memory");
    SB(); BAR(); SB();
  }
#undef STG
#undef READ_B2
#undef READ_A
#undef MFMA16

  const int c0 = bn + wn * 64 + lr;
  if (BF16_OUT) {
    unsigned short* C = (unsigned short*)Cout;
    #pragma unroll
    for (int mf = 0; mf < 8; ++mf)
      #pragma unroll
      for (int i = 0; i < 4; ++i) {
        size_t r = (size_t)(bm + wm * 128 + (mf >> 2) * 64 + (mf & 3) * 16 + lq * 4 + i);
        #pragma unroll
        for (int nf = 0; nf < 4; ++nf)
          C[r * ldc + c0 + (nf >> 1) * 32 + (nf & 1) * 16] = f2bf(acc[mf][nf][i]);
      }
  } else {
    float* C = (float*)Cout;
    float bv[4];
    #pragma unroll
    for (int nf = 0; nf < 4; ++nf)
      bv[nf] = bias ? bias[c0 + (nf >> 1) * 32 + (nf & 1) * 16] : 0.f;
    #pragma unroll
    for (int mf = 0; mf < 8; ++mf)
      #pragma unroll
      for (int i = 0; i < 4; ++i) {
        size_t r = (size_t)(bm + wm * 128 + (mf >> 2) * 64 + (mf & 3) * 16 + lq * 4 + i);
        #pragma unroll
        for (int nf = 0; nf < 4; ++nf)
          C[r * ldc + c0 + (nf >> 1) * 32 + (nf & 1) * 16] = acc[mf][nf][i] + bv[nf];
      }
  }
}

// -------------------------------- 128x256-tile variant (grouped-B capable) ----
// C[M,N] = A[M,K](lda) * BTg[N,K]^T where BTg = BT + (bm>>10)*gstride.
// panels/buf = {B0,B1,A}; 6 slots = 96KB; wave tile 64x64.
template<int BF16_OUT>
__global__ __launch_bounds__(512, 1) void gemm128(
    const unsigned short* __restrict__ A, int lda,
    const unsigned short* __restrict__ BT, size_t gstride,
    void* __restrict__ Cout, const float* __restrict__ bias,
    int ldc, int K) {
  constexpr int PAN = 16384;
  __shared__ __align__(16) char lds[6 * PAN];      // 96 KiB
  const int tid = threadIdx.x;
  const int ln = tid & 63, w = tid >> 6;
  const int lr = ln & 15, lq = ln >> 4;
  const int wm = w >> 2, wn = w & 3;

  int wid = blockIdx.y * gridDim.x + blockIdx.x;
  const int nwg = gridDim.x * gridDim.y;
  { const int q = nwg >> 3; wid = (wid & 7) * q + (wid >> 3); }
  const int bm = (wid / gridDim.x) * 128, bn = (wid % gridDim.x) * 256;

  const int srow = tid >> 3;
  const int csw = ((tid & 7) ^ (srow & 7)) * 8;
  const unsigned short* BTg = BT + (size_t)(bm >> 10) * gstride;
  const unsigned short* rB0 = BTg + (size_t)(bn + srow) * K + csw;
  const unsigned short* rB1 = rB0 + (size_t)128 * K;
  const unsigned short* rA0 = A + (size_t)(bm + srow) * lda + csw;
  const size_t rowB = (size_t)64 * K;
  const size_t rowA = (size_t)64 * lda;
  char* ldst = lds + tid * 16;

#define STGB(slot, src, t) do {                                              \
    async_ld16((src) + (size_t)(t) * 64,        ldst + (slot) * PAN);        \
    async_ld16((src) + (size_t)(t) * 64 + rowB, ldst + (slot) * PAN + 8192); \
  } while (0)
#define STGA(slot, src, t) do {                                              \
    async_ld16((src) + (size_t)(t) * 64,        ldst + (slot) * PAN);        \
    async_ld16((src) + (size_t)(t) * 64 + rowA, ldst + (slot) * PAN + 8192); \
  } while (0)

  const int sw0 = ((0 + lq) ^ (lr & 7)) * 16;
  const int sw1 = ((4 + lq) ^ (lr & 7)) * 16;
  const char* Arow = lds + (wm * 64 + lr) * 128;
  const char* Brow = lds + ((wn & 1) * 64 + lr) * 128;

  bf16x8 a[4], b[4];
  f32x4 acc[4][4] = {};

#define RD(ph_sw, Ap, Bp)                                                    \
    _Pragma("unroll")                                                        \
    for (int nf = 0; nf < 4; ++nf) b[nf] = *(const bf16x8*)((Bp) + nf * 2048 + (ph_sw)); \
    _Pragma("unroll")                                                        \
    for (int fi = 0; fi < 4; ++fi) a[fi] = *(const bf16x8*)((Ap) + fi * 2048 + (ph_sw));
#define MM16()                                                               \
    __builtin_amdgcn_s_setprio(1);                                           \
    _Pragma("unroll")                                                        \
    for (int fi = 0; fi < 4; ++fi)                                           \
      _Pragma("unroll")                                                      \
      for (int nf = 0; nf < 4; ++nf)                                         \
        acc[fi][nf] = __builtin_amdgcn_mfma_f32_16x16x32_bf16(a[fi], b[nf], acc[fi][nf], 0, 0, 0); \
    __builtin_amdgcn_s_setprio(0);

  STGB(0, rB0, 0); STGB(1, rB1, 0); STGA(2, rA0, 0);
  STGB(3, rB0, 1); STGB(4, rB1, 1); STGA(5, rA0, 1);
  asm volatile("s_waitcnt vmcnt(6)" ::: "memory");
  SB(); BAR(); SB();

  const int NT = K / 64;
  for (int t = 0; t < NT; ++t) {
    const int par = (t & 1) * 3;
    const char* Ap = Arow + (par + 2) * PAN;
    const char* Bp = Brow + (par + (wn >> 1)) * PAN;
    RD(sw0, Ap, Bp);
    SB(); BAR(); SB();
    MM16();
    SB(); BAR(); SB();
    RD(sw1, Ap, Bp);
    SB(); BAR(); SB();
    MM16();
    if (t + 2 < NT) {
      STGB(par + 0, rB0, t + 2); STGB(par + 1, rB1, t + 2); STGA(par + 2, rA0, t + 2);
      asm volatile("s_waitcnt vmcnt(6)" ::: "memory");
    } else if (t == NT - 2) {
      asm volatile("s_waitcnt vmcnt(0)" ::: "memory");
    }
    SB(); BAR(); SB();
  }
#undef STGB
#undef STGA
#undef RD
#undef MM16

  const int c0 = bn + wn * 64 + lr;
  if (BF16_OUT) {
    unsigned short* C = (unsigned short*)Cout;
    #pragma unroll
    for (int fi = 0; fi < 4; ++fi)
      #pragma unroll
      for (int i = 0; i < 4; ++i) {
        size_t r = (size_t)(bm + wm * 64 + fi * 16 + lq * 4 + i);
        #pragma unroll
        for (int nf = 0; nf < 4; ++nf)
          C[r * ldc + c0 + (nf >> 1) * 32 + (nf & 1) * 16] = f2bf(acc[fi][nf][i]);
      }
  } else {
    float* C = (float*)Cout;
    float bv[4];
    #pragma unroll
    for (int nf = 0; nf < 4; ++nf)
      bv[nf] = bias ? bias[c0 + (nf >> 1) * 32 + (nf & 1) * 16] : 0.f;
    #pragma unroll
    for (int fi = 0; fi < 4; ++fi)
      #pragma unroll
      for (int i = 0; i < 4; ++i) {
        size_t r = (size_t)(bm + wm * 64 + fi * 16 + lq * 4 + i);
        #pragma unroll
        for (int nf = 0; nf < 4; ++nf)
          C[r * ldc + c0 + (nf >> 1) * 32 + (nf & 1) * 16] = acc[fi][nf][i] + bv[nf];
      }
  }
}

// --------------------------------- partial M^T = scale*(k^T v)^T over j ----
__global__ __launch_bounds__(256) void kv_outer(
    const unsigned short* __restrict__ qkv,
    unsigned short* __restrict__ MT, float scale) {
  const int bid = blockIdx.x;
  const int p = bid & 3, unit = bid >> 2;
  const int b = unit >> 5, h = (unit >> 1) & 15, hf = unit & 1;
  const size_t base = ((size_t)(b * 2048 + hf * 1024)) * 3072 + h * 64;
  const unsigned short* kp = qkv + base + 1024;
  const unsigned short* vp = qkv + base + 2048;
  __shared__ __align__(16) unsigned short kT[64][136];
  __shared__ __align__(16) unsigned short vT[64][136];
  const int tid = threadIdx.x, wv = tid >> 6, ln = tid & 63;
  f32x4 acc[4] = {};
  const int e4 = (tid & 15) * 4;
  const int jr = tid >> 4;
  const int fr = ln & 15, ko = (ln >> 4) * 8;

  for (int j0 = p * 256; j0 < p * 256 + 256; j0 += 128) {
    __syncthreads();
    #pragma unroll
    for (int jj = 0; jj < 128; jj += 16) {
      int j = jj + jr;
      size_t go = (size_t)(j0 + j) * 3072 + e4;
      short4v k4 = *(const short4v*)(kp + go);
      short4v v4 = *(const short4v*)(vp + go);
      #pragma unroll
      for (int t = 0; t < 4; t++) {
        kT[e4 + t][j] = (unsigned short)k4[t];
        vT[e4 + t][j] = (unsigned short)v4[t];
      }
    }
    __syncthreads();
    #pragma unroll
    for (int kk = 0; kk < 128; kk += 32) {
      bf16x8 af = *(const bf16x8*)&kT[wv * 16 + fr][kk + ko];
      #pragma unroll
      for (int n = 0; n < 4; n++) {
        bf16x8 bf2 = *(const bf16x8*)&vT[n * 16 + fr][kk + ko];
        acc[n] = __builtin_amdgcn_mfma_f32_16x16x32_bf16(af, bf2, acc[n], 0, 0, 0);
      }
    }
  }
  unsigned short* outp = MT + (size_t)bid * 4096;       // [d][e], 64x64
  #pragma unroll
  for (int n = 0; n < 4; n++)
    #pragma unroll
    for (int i = 0; i < 4; i++) {
      int d = n * 16 + fr;
      int e = wv * 16 + (ln >> 4) * 4 + i;
      outp[d * 64 + e] = f2bf(acc[n][i] * scale);
    }
}

// ---------------- W2T[g][:, h-block] = wprojT[:, h-block] @ M_h (64x64) ----
// g = b*2 + hf_q consumes unit = b*32 + h*2 + (1-hf_q).  128 blocks (g,h).
__global__ __launch_bounds__(256) void w2k(
    const unsigned short* __restrict__ MTp,
    const unsigned short* __restrict__ wprojT,
    unsigned short* __restrict__ w2t) {
  const int g = blockIdx.x >> 4, h = blockIdx.x & 15;
  const int b = g >> 1, hfq = g & 1;
  const int unit = b * 32 + h * 2 + (1 - hfq);
  const unsigned short* mp = MTp + (size_t)(unit * 4) * 4096;
  __shared__ unsigned short Ms[64][72];     // Ms[e][d] = sum_p M^T_p[d][e]
  const int tid = threadIdx.x;
  {
    const int d = tid >> 2, eb = (tid & 3) * 16;
    #pragma unroll
    for (int j = 0; j < 16; ++j) {
      float s = 0.f;
      #pragma unroll
      for (int p = 0; p < 4; ++p)
        s += bf2f(mp[p * 4096 + d * 64 + eb + j]);
      Ms[eb + j][d] = f2bf(s);
    }
  }
  __syncthreads();
  const int w = tid >> 6, ln = tid & 63;
  const int fr = ln & 15, lq = ln >> 4, ko = lq * 8;
  bf16x8 bb[4][2];
  #pragma unroll
  for (int nf = 0; nf < 4; ++nf)
    #pragma unroll
    for (int ks = 0; ks < 2; ++ks)
      bb[nf][ks] = *(const bf16x8*)&Ms[nf * 16 + fr][ks * 32 + ko];
  const unsigned short* ap = wprojT + h * 64;
  unsigned short* op = w2t + (size_t)g * 1048576 + h * 64;
  #pragma unroll 4
  for (int cf = 0; cf < 16; ++cf) {
    const int crow = w * 256 + cf * 16;
    f32x4 acc[4] = {};
    #pragma unroll
    for (int ks = 0; ks < 2; ++ks) {
      bf16x8 a = *(const bf16x8*)(ap + (size_t)(crow + fr) * 1024 + ks * 32 + ko);
      #pragma unroll
      for (int nf = 0; nf < 4; ++nf)
        acc[nf] = __builtin_amdgcn_mfma_f32_16x16x32_bf16(a, bb[nf][ks], acc[nf], 0, 0, 0);
    }
    #pragma unroll
    for (int nf = 0; nf < 4; ++nf)
      #pragma unroll
      for (int i = 0; i < 4; ++i)
        op[(size_t)(crow + lq * 4 + i) * 1024 + nf * 16 + fr] = f2bf(acc[nf][i]);
  }
}

// ---------------------------------------------------------------------------
extern "C" void kernel_launch(void* const* d_in, const int* in_sizes, int n_in,
                              void* d_out, int out_size, void* d_ws, size_t ws_size,
                              hipStream_t stream) {
  const float* x     = (const float*)d_in[0];   // 4 x 2048 x 1024
  const float* Wqkv  = (const float*)d_in[1];   // 1024 x 3072
  const float* Wproj = (const float*)d_in[2];   // 1024 x 1024
  const float* bproj = (const float*)d_in[3];   // 1024
  float* out = (float*)d_out;                   // 8192 x 1024

  char* ws = (char*)d_ws;
  unsigned short* xb     = (unsigned short*)(ws);               // 16.78 MB (dead after v-GEMM)
  unsigned short* W2T    = (unsigned short*)(ws);               // 16.0 MB, aliases xb
  unsigned short* wqkvT  = (unsigned short*)(ws + 16777216);    //  6.29 MB
  unsigned short* wprojT = (unsigned short*)(ws + 23068672);    //  2.10 MB
  unsigned short* qkv    = (unsigned short*)(ws + 25165824);    // 50.33 MB
  unsigned short* MT     = (unsigned short*)(ws + 75497472);    //  2.10 MB
  // total: 77.6 MB

  // fused cast + weight transposes
  prep<<<12288, 256, 0, stream>>>(x, Wqkv, Wproj, xb, wqkvT, wprojT);

  // qk = x @ W_qkv[:, :2048] -> qkv cols 0..2047.  grid 8x32 = 256 exact.
  gemm8t<1><<<dim3(8, 32), 512, 0, stream>>>(xb, wqkvT, (void*)qkv, nullptr,
                                             3072, 1024);
  // v = x @ W_qkv[:, 2048:] -> qkv cols 2048..3071.  grid 4x64 = 256 exact.
  gemm128<1><<<dim3(4, 64), 512, 0, stream>>>(xb, 1024,
                                              wqkvT + (size_t)2048 * 1024, 0,
                                              (void*)(qkv + 2048), nullptr,
                                              3072, 1024);

  // partial M^T per (b,h,half, j-quarter) — 512 blocks
  kv_outer<<<512, 256, 0, stream>>>(qkv, MT, 0.125f);

  // W2T[g] = wprojT @ blockdiag(M_g)  — 128 blocks (g,h)
  w2k<<<128, 256, 0, stream>>>(MT, wprojT, W2T);

  // out = q @ W2T[group]^T + b  (fp32), q read in place (lda=3072).
  // grid 4x64 = 256 exact; groups are 1024-row aligned (8 tiles/group).
  gemm128<0><<<dim3(4, 64), 512, 0, stream>>>(qkv, 3072,
                                              W2T, (size_t)1048576,
                                              (void*)out, bproj,
                                              1024, 1024);
}